// Round 5
// baseline (119.634 us; speedup 1.0000x reference)
//
#include <hip/hip_runtime.h>
#include <math.h>

#define D_DIM 2048
#define M_EV  16384
#define LCH   32
#define CCH   (M_EV / LCH)      // 512 chunks
#define SEG   32                // chunks per scan segment
#define NSEG  (CCH / SEG)       // 16 segments
#define BETA  1.0f

__device__ __forceinline__ float softplus_f(float x){
  float e = __expf(-fabsf(x));
  return fmaxf(x, 0.0f) + __logf(1.0f + e);
}

// float -> bf16 (RNE); inputs are finite non-negative here.
__device__ __forceinline__ unsigned short f2bf(float f){
  unsigned b = __float_as_uint(f);
  return (unsigned short)((b + 0x7FFFu + ((b >> 16) & 1u)) >> 16);
}
__device__ __forceinline__ float bf2f(unsigned short u){
  return __uint_as_float(((unsigned)u) << 16);
}

// T_max arrives as a 1-element array; decode int-vs-float defensively.
__device__ __forceinline__ float decode_T(const void* p){
  unsigned bits = *(const unsigned*)p;
  float fv = __uint_as_float(bits);
  return (fv >= 1e-3f && fv <= 1e7f) ? fv : (float)(int)bits;
}

__device__ __forceinline__ float wave_red(float v){
  #pragma unroll
  for (int o = 32; o > 0; o >>= 1) v += __shfl_down(v, o);
  return v;
}

// Fused small-work kernel. Block ranges:
//   [0,8)   : muw[j] = softplus(log_mu)+eps ; acc[2] += sum(mu)
//   [8,72)  : per event i: contrib[m_i] += 1-exp(-beta*(T-t_i))
//             AND Lsum scatter SL[c][m_i] += exp(-beta*(t_{(c+1)L}-t_i))
//   [72,74) : dchunk/cumdec per chunk (+ Aseg per segment in block 72)
__global__ void k_small(const float* __restrict__ t, const int* __restrict__ m,
                        const void* Tp, const float* __restrict__ log_mu,
                        float* __restrict__ muw, float* __restrict__ contrib,
                        float* __restrict__ SL, float* __restrict__ dchunk,
                        float* __restrict__ cumdec, float* __restrict__ Aseg,
                        float* __restrict__ acc){
  const int b = blockIdx.x, tid = threadIdx.x;
  if (b < 8){
    int j = b*256 + tid;
    float v = softplus_f(log_mu[j]) + 1e-6f;
    muw[j] = v;
    float s = wave_red(v);
    if ((tid & 63) == 0) atomicAdd(&acc[2], s);
  } else if (b < 72){
    int i = (b-8)*256 + tid;
    int d = m[i];
    float ti = t[i];
    float T = decode_T(Tp);
    atomicAdd(&contrib[d], 1.0f - __expf(-BETA * (T - ti)));
    int c = i >> 5;
    if (c < CCH - 1){                       // last chunk's carry is unused
      float tn = t[(c+1)*LCH];
      atomicAdd(&SL[(size_t)c * D_DIM + d], __expf(-BETA * (tn - ti)));
    }
  } else {
    int c = (b-72)*256 + tid;               // c in [0,512)
    float tc = t[c*LCH];
    dchunk[c] = (c < CCH-1) ? __expf(-BETA * (t[(c+1)*LCH] - tc)) : 1.0f;
    int s0c = (c >> 5) << 5;                // segment-start chunk
    cumdec[c] = __expf(-BETA * (tc - t[s0c*LCH]));
    if (b == 72 && tid < NSEG){
      int s = tid;
      Aseg[s] = (s < NSEG-1)
        ? __expf(-BETA * (t[(s+1)*SEG*LCH] - t[s*SEG*LCH])) : 1.0f;
    }
  }
}

// Local exclusive scan within each segment (in-place), carry-out per segment.
__global__ void k_scan_local(float* __restrict__ SL,
                             const float* __restrict__ dchunk,
                             float* __restrict__ Carry){
  const int tid = threadIdx.x;
  const int seg = blockIdx.x >> 3, jb = blockIdx.x & 7;
  const int j = jb*256 + tid;
  const int c0 = seg * SEG;
  const size_t base = (size_t)c0 * D_DIM + j;
  float u = 0.f;
  float cur[4], nxt[4];
  #pragma unroll
  for (int q = 0; q < 4; ++q) cur[q] = SL[base + (size_t)q * D_DIM];
  for (int g = 0; g < SEG; g += 4){
    #pragma unroll
    for (int q = 0; q < 4; ++q)
      nxt[q] = (g+4 < SEG) ? SL[base + (size_t)(g+4+q) * D_DIM] : 0.f;
    #pragma unroll
    for (int q = 0; q < 4; ++q){
      int c = c0 + g + q;
      float l = cur[q];
      SL[(size_t)c * D_DIM + j] = u;
      u = fmaf(dchunk[c], u, l);
    }
    #pragma unroll
    for (int q = 0; q < 4; ++q) cur[q] = nxt[q];
  }
  Carry[(size_t)seg * D_DIM + j] = u;
}

// Fused: blocks [0,8) scan the segment carries (E = entering state);
// blocks [8,520) compute sA = bf16(softplus(log_alpha)) and the integral
// partial acc[1] += softplus(la)·contrib. Independent work, both only need
// k_small/k_scan_local results.
__global__ void k_carry_alpha(const float* __restrict__ Carry,
                              const float* __restrict__ Aseg,
                              float* __restrict__ E,
                              const float* __restrict__ la,
                              const float* __restrict__ contrib,
                              unsigned short* __restrict__ sA,
                              float* __restrict__ acc){
  const int b = blockIdx.x, tid = threadIdx.x;
  if (b < 8){
    const int j = b*256 + tid;
    float cr[NSEG];
    #pragma unroll
    for (int s = 0; s < NSEG; ++s) cr[s] = Carry[(size_t)s * D_DIM + j];
    float e = 0.f;
    #pragma unroll
    for (int s = 0; s < NSEG; ++s){
      E[(size_t)s * D_DIM + j] = e;
      e = fmaf(Aseg[s], e, cr[s]);
    }
    return;
  }
  const int nthreads = 512*256;               // alpha-range threads
  int atid = (b-8)*256 + tid;
  const float4* la4 = (const float4*)la;
  ushort4* sA4 = (ushort4*)sA;
  float p = 0.f;
  #pragma unroll
  for (int u = 0; u < 8; ++u){
    int i4 = atid + u * nthreads;
    float4 x = la4[i4];
    float4 sp;
    sp.x = softplus_f(x.x); sp.y = softplus_f(x.y);
    sp.z = softplus_f(x.z); sp.w = softplus_f(x.w);
    ushort4 h;
    h.x = f2bf(sp.x); h.y = f2bf(sp.y); h.z = f2bf(sp.z); h.w = f2bf(sp.w);
    sA4[i4] = h;
    int col = (i4 * 4) & (D_DIM - 1);
    p = fmaf(sp.x, contrib[col+0], p);
    p = fmaf(sp.y, contrib[col+1], p);
    p = fmaf(sp.z, contrib[col+2], p);
    p = fmaf(sp.w, contrib[col+3], p);
  }
  __shared__ float red[4];
  float w = wave_red(p);
  int lane = tid & 63, wid = tid >> 6;
  if (lane == 0) red[wid] = w;
  __syncthreads();
  if (tid == 0) atomicAdd(&acc[1], red[0]+red[1]+red[2]+red[3]);
}

// One block (512 thr) per chunk. Thread owns 4 cols of S in registers.
// bf16 rows, depth-8 prefetch, per-event decay precomputed in LDS, no barrier
// in the event loop. Last block to finish (atomic ticket) writes out[0].
__global__ __launch_bounds__(512) void k_events(
    const float* __restrict__ t, const int* __restrict__ m,
    const unsigned short* __restrict__ sA, const float* __restrict__ muw,
    const float* __restrict__ SL, const float* __restrict__ E,
    const float* __restrict__ cumdec, float* __restrict__ acc,
    const void* Tp, float* __restrict__ out){
  __shared__ int   ml[LCH];
  __shared__ float decs[LCH];
  __shared__ float red[LCH][8];
  const int tid = threadIdx.x;          // 0..511
  const int c = blockIdx.x;
  const int seg = c >> 5;
  const float cd = cumdec[c];

  const float4 sv = *(const float4*)(SL + (size_t)c  * D_DIM + tid*4);
  const float4 ev = *(const float4*)(E  + (size_t)seg * D_DIM + tid*4);
  float4 s;
  s.x = fmaf(ev.x, cd, sv.x); s.y = fmaf(ev.y, cd, sv.y);
  s.z = fmaf(ev.z, cd, sv.z); s.w = fmaf(ev.w, cd, sv.w);

  if (tid < LCH){
    ml[tid] = m[c*LCH + tid];
    float tk = t[c*LCH + tid];
    float tp = (tid == 0) ? tk : t[c*LCH + tid - 1];
    decs[tid] = __expf(-BETA * (tk - tp));   // ==1 for k==0
  }
  __syncthreads();

  const int lane = tid & 63, wid = tid >> 6;
  const int colb = tid * 4;

  ushort4 pf0 = *(const ushort4*)(sA + (size_t)ml[0] * D_DIM + colb);
  ushort4 pf1 = *(const ushort4*)(sA + (size_t)ml[1] * D_DIM + colb);
  ushort4 pf2 = *(const ushort4*)(sA + (size_t)ml[2] * D_DIM + colb);
  ushort4 pf3 = *(const ushort4*)(sA + (size_t)ml[3] * D_DIM + colb);
  ushort4 pf4 = *(const ushort4*)(sA + (size_t)ml[4] * D_DIM + colb);
  ushort4 pf5 = *(const ushort4*)(sA + (size_t)ml[5] * D_DIM + colb);
  ushort4 pf6 = *(const ushort4*)(sA + (size_t)ml[6] * D_DIM + colb);
  ushort4 pf7 = *(const ushort4*)(sA + (size_t)ml[7] * D_DIM + colb);

#define STAGE(Q) {                                                          \
    const int kk = k + (Q);                                                 \
    const int d = ml[kk];                                                   \
    const int kn = (kk + 8 < LCH) ? kk + 8 : LCH - 1;                       \
    ushort4 nx = *(const ushort4*)(sA + (size_t)ml[kn] * D_DIM + colb);     \
    const float dec = decs[kk];                                             \
    s.x *= dec; s.y *= dec; s.z *= dec; s.w *= dec;                         \
    float p = 0.f;                                                          \
    p = fmaf(bf2f(pf##Q.x), s.x, p);                                        \
    p = fmaf(bf2f(pf##Q.y), s.y, p);                                        \
    p = fmaf(bf2f(pf##Q.z), s.z, p);                                        \
    p = fmaf(bf2f(pf##Q.w), s.w, p);                                        \
    if ((d >> 2) == tid){                                                   \
      int r = d & 3;                                                        \
      s.x += (r==0) ? 1.f : 0.f; s.y += (r==1) ? 1.f : 0.f;                 \
      s.z += (r==2) ? 1.f : 0.f; s.w += (r==3) ? 1.f : 0.f;                 \
    }                                                                       \
    float w = wave_red(p);                                                  \
    if (lane == 0) red[kk][wid] = w;                                        \
    pf##Q = nx;                                                             \
  }

  for (int k = 0; k < LCH; k += 8){
    STAGE(0) STAGE(1) STAGE(2) STAGE(3)
    STAGE(4) STAGE(5) STAGE(6) STAGE(7)
  }
#undef STAGE

  __syncthreads();
  float lg = 0.f;
  if (tid < LCH){
    const float* r = red[tid];
    float lam = muw[ml[tid]] + ((r[0]+r[1])+(r[2]+r[3]))
                             + ((r[4]+r[5])+(r[6]+r[7]));
    lg = __logf(lam + 1e-8f);
  }
  if (tid < 64){
    float w = wave_red(lg);
    if (tid == 0){
      atomicAdd(&acc[0], w);
      __threadfence();                        // publish before taking ticket
      unsigned old = atomicAdd((unsigned*)&acc[3], 1u);
      if (old == CCH - 1){                    // last block: finalize
        float a0 = atomicAdd(&acc[0], 0.0f);  // device-scope reads
        float a1 = atomicAdd(&acc[1], 0.0f);
        float a2 = atomicAdd(&acc[2], 0.0f);
        float T = decode_T(Tp);
        out[0] = a0 - (T * a2 + a1 * (1.0f / BETA));
      }
    }
  }
}

extern "C" void kernel_launch(void* const* d_in, const int* in_sizes, int n_in,
                              void* d_out, int out_size, void* d_ws, size_t ws_size,
                              hipStream_t stream) {
  const float* t_events  = (const float*)d_in[0];
  const int*   marks     = (const int*)  d_in[1];
  const void*  Tp        =               d_in[2];
  const float* log_mu    = (const float*)d_in[3];
  const float* log_alpha = (const float*)d_in[4];
  float* out = (float*)d_out;

  // ws layout (floats), zeroed region first:
  // SL[CCH*D] | contrib[D] | acc[16] || Carry[NSEG*D] | E[NSEG*D] | muw[D]
  //   | dchunk[CCH] | cumdec[CCH] | Aseg[NSEG] | sA[D*D bf16]
  float* ws      = (float*)d_ws;
  float* SL      = ws;
  float* contrib = SL + (size_t)CCH * D_DIM;
  float* acc     = contrib + D_DIM;
  float* Carry   = acc + 16;
  float* E       = Carry + (size_t)NSEG * D_DIM;
  float* muw     = E + (size_t)NSEG * D_DIM;
  float* dchunk  = muw + D_DIM;
  float* cumdec  = dchunk + CCH;
  float* Aseg    = cumdec + CCH;
  unsigned short* sA = (unsigned short*)(Aseg + NSEG);  // 16B-aligned offset

  size_t zero_floats = (size_t)CCH * D_DIM + D_DIM + 16;
  hipMemsetAsync(d_ws, 0, zero_floats * sizeof(float), stream);

  k_small      <<<74, 256, 0, stream>>>(t_events, marks, Tp, log_mu, muw,
                                        contrib, SL, dchunk, cumdec, Aseg, acc);
  k_scan_local <<<NSEG*8, 256, 0, stream>>>(SL, dchunk, Carry);
  k_carry_alpha<<<520, 256, 0, stream>>>(Carry, Aseg, E, log_alpha,
                                         contrib, sA, acc);
  k_events     <<<CCH, 512, 0, stream>>>(t_events, marks, sA, muw,
                                         SL, E, cumdec, acc, Tp, out);
}

// Round 6
// 114.486 us; speedup vs baseline: 1.0450x; 1.0450x over previous
//
#include <hip/hip_runtime.h>
#include <math.h>

#define D_DIM 2048
#define M_EV  16384
#define LCH   32
#define CCH   (M_EV / LCH)      // 512 chunks
#define SEG   32                // chunks per scan segment
#define NSEG  (CCH / SEG)       // 16 segments
#define BETA  1.0f

__device__ __forceinline__ float softplus_f(float x){
  float e = __expf(-fabsf(x));
  return fmaxf(x, 0.0f) + __logf(1.0f + e);
}

// float -> bf16 (RNE); inputs are finite non-negative here.
__device__ __forceinline__ unsigned short f2bf(float f){
  unsigned b = __float_as_uint(f);
  return (unsigned short)((b + 0x7FFFu + ((b >> 16) & 1u)) >> 16);
}
__device__ __forceinline__ float bf2f(unsigned short u){
  return __uint_as_float(((unsigned)u) << 16);
}

// T_max arrives as a 1-element array; decode int-vs-float defensively.
__device__ __forceinline__ float decode_T(const void* p){
  unsigned bits = *(const unsigned*)p;
  float fv = __uint_as_float(bits);
  return (fv >= 1e-3f && fv <= 1e7f) ? fv : (float)(int)bits;
}

__device__ __forceinline__ float wave_red(float v){
  #pragma unroll
  for (int o = 32; o > 0; o >>= 1) v += __shfl_down(v, o);
  return v;
}

// Fused small-work kernel. Block ranges:
//   [0,8)   : muw[j] = softplus(log_mu)+eps ; acc[2] += sum(mu)
//   [8,72)  : per event i: contrib[m_i] += 1-exp(-beta*(T-t_i))
//             AND Lsum scatter SL[c][m_i] += exp(-beta*(t_{(c+1)L}-t_i))
//   [72,74) : dchunk/cumdec per chunk (+ Aseg per segment in block 72)
__global__ void k_small(const float* __restrict__ t, const int* __restrict__ m,
                        const void* Tp, const float* __restrict__ log_mu,
                        float* __restrict__ muw, float* __restrict__ contrib,
                        float* __restrict__ SL, float* __restrict__ dchunk,
                        float* __restrict__ cumdec, float* __restrict__ Aseg,
                        float* __restrict__ acc){
  const int b = blockIdx.x, tid = threadIdx.x;
  if (b < 8){
    int j = b*256 + tid;
    float v = softplus_f(log_mu[j]) + 1e-6f;
    muw[j] = v;
    float s = wave_red(v);
    if ((tid & 63) == 0) atomicAdd(&acc[2], s);
  } else if (b < 72){
    int i = (b-8)*256 + tid;
    int d = m[i];
    float ti = t[i];
    float T = decode_T(Tp);
    atomicAdd(&contrib[d], 1.0f - __expf(-BETA * (T - ti)));
    int c = i >> 5;
    if (c < CCH - 1){                       // last chunk's carry is unused
      float tn = t[(c+1)*LCH];
      atomicAdd(&SL[(size_t)c * D_DIM + d], __expf(-BETA * (tn - ti)));
    }
  } else {
    int c = (b-72)*256 + tid;               // c in [0,512)
    float tc = t[c*LCH];
    dchunk[c] = (c < CCH-1) ? __expf(-BETA * (t[(c+1)*LCH] - tc)) : 1.0f;
    int s0c = (c >> 5) << 5;                // segment-start chunk
    cumdec[c] = __expf(-BETA * (tc - t[s0c*LCH]));
    if (b == 72 && tid < NSEG){
      int s = tid;
      Aseg[s] = (s < NSEG-1)
        ? __expf(-BETA * (t[(s+1)*SEG*LCH] - t[s*SEG*LCH])) : 1.0f;
    }
  }
}

// Local exclusive scan within each segment (in-place), carry-out per segment.
__global__ void k_scan_local(float* __restrict__ SL,
                             const float* __restrict__ dchunk,
                             float* __restrict__ Carry){
  const int tid = threadIdx.x;
  const int seg = blockIdx.x >> 3, jb = blockIdx.x & 7;
  const int j = jb*256 + tid;
  const int c0 = seg * SEG;
  const size_t base = (size_t)c0 * D_DIM + j;
  float u = 0.f;
  float cur[4], nxt[4];
  #pragma unroll
  for (int q = 0; q < 4; ++q) cur[q] = SL[base + (size_t)q * D_DIM];
  for (int g = 0; g < SEG; g += 4){
    #pragma unroll
    for (int q = 0; q < 4; ++q)
      nxt[q] = (g+4 < SEG) ? SL[base + (size_t)(g+4+q) * D_DIM] : 0.f;
    #pragma unroll
    for (int q = 0; q < 4; ++q){
      int c = c0 + g + q;
      float l = cur[q];
      SL[(size_t)c * D_DIM + j] = u;
      u = fmaf(dchunk[c], u, l);
    }
    #pragma unroll
    for (int q = 0; q < 4; ++q) cur[q] = nxt[q];
  }
  Carry[(size_t)seg * D_DIM + j] = u;
}

// Fused: blocks [0,8) scan the segment carries (E = entering state);
// blocks [8,520) compute sA = bf16(softplus(log_alpha)) and the integral
// partial acc[1] += softplus(la)·contrib.
__global__ void k_carry_alpha(const float* __restrict__ Carry,
                              const float* __restrict__ Aseg,
                              float* __restrict__ E,
                              const float* __restrict__ la,
                              const float* __restrict__ contrib,
                              unsigned short* __restrict__ sA,
                              float* __restrict__ acc){
  const int b = blockIdx.x, tid = threadIdx.x;
  if (b < 8){
    const int j = b*256 + tid;
    float cr[NSEG];
    #pragma unroll
    for (int s = 0; s < NSEG; ++s) cr[s] = Carry[(size_t)s * D_DIM + j];
    float e = 0.f;
    #pragma unroll
    for (int s = 0; s < NSEG; ++s){
      E[(size_t)s * D_DIM + j] = e;
      e = fmaf(Aseg[s], e, cr[s]);
    }
    return;
  }
  const int nthreads = 512*256;               // alpha-range threads
  int atid = (b-8)*256 + tid;
  const float4* la4 = (const float4*)la;
  ushort4* sA4 = (ushort4*)sA;
  float p = 0.f;
  #pragma unroll
  for (int u = 0; u < 8; ++u){
    int i4 = atid + u * nthreads;
    float4 x = la4[i4];
    float4 sp;
    sp.x = softplus_f(x.x); sp.y = softplus_f(x.y);
    sp.z = softplus_f(x.z); sp.w = softplus_f(x.w);
    ushort4 h;
    h.x = f2bf(sp.x); h.y = f2bf(sp.y); h.z = f2bf(sp.z); h.w = f2bf(sp.w);
    sA4[i4] = h;
    int col = (i4 * 4) & (D_DIM - 1);
    p = fmaf(sp.x, contrib[col+0], p);
    p = fmaf(sp.y, contrib[col+1], p);
    p = fmaf(sp.z, contrib[col+2], p);
    p = fmaf(sp.w, contrib[col+3], p);
  }
  __shared__ float red[4];
  float w = wave_red(p);
  int lane = tid & 63, wid = tid >> 6;
  if (lane == 0) red[wid] = w;
  __syncthreads();
  if (tid == 0) atomicAdd(&acc[1], red[0]+red[1]+red[2]+red[3]);
}

// One block (512 thr = 8 waves) per chunk. Decomposed (no sequential S):
//   lam_k = mu[d_k] + e^{-(t_k-t0)} * (sA[d_k] . S0)
//                   + sum_{i<k} e^{-(t_k-t_i)} * sA[d_k][m_i]
// Wave w owns events 4w..4w+3. Lane holds 32 S0 cols in registers; per event:
// 8 ushort4 row loads + 32 FMA + one wave_red. Waves fully independent.
__global__ __launch_bounds__(512) void k_events(
    const float* __restrict__ t, const int* __restrict__ m,
    const unsigned short* __restrict__ sA, const float* __restrict__ muw,
    const float* __restrict__ SL, const float* __restrict__ E,
    const float* __restrict__ cumdec, float* __restrict__ acc,
    const void* Tp, float* __restrict__ out){
  __shared__ float S0[D_DIM];
  __shared__ float tl[LCH];
  __shared__ int   ml[LCH];
  __shared__ float wred[8];
  const int tid = threadIdx.x;          // 0..511
  const int c = blockIdx.x;
  const int seg = c >> 5;
  const float cd = cumdec[c];

  {
    const float4 sv = *(const float4*)(SL + (size_t)c  * D_DIM + tid*4);
    const float4 ev = *(const float4*)(E  + (size_t)seg * D_DIM + tid*4);
    float4 s;
    s.x = fmaf(ev.x, cd, sv.x); s.y = fmaf(ev.y, cd, sv.y);
    s.z = fmaf(ev.z, cd, sv.z); s.w = fmaf(ev.w, cd, sv.w);
    *(float4*)&S0[tid*4] = s;
  }
  if (tid < LCH){
    ml[tid] = m[c*LCH + tid];
    tl[tid] = t[c*LCH + tid];
  }
  __syncthreads();

  const int l = tid & 63, w = tid >> 6;
  const int l4 = l * 4;

  // lane's 32 S0 columns -> registers (one-time)
  float4 s0[8];
  #pragma unroll
  for (int u = 0; u < 8; ++u) s0[u] = *(const float4*)&S0[u*256 + l4];

  const float t0 = tl[0];
  float lgw = 0.f;
  #pragma unroll
  for (int q = 0; q < 4; ++q){
    const int k = w*4 + q;
    const int d = ml[k];
    const unsigned short* row = sA + (size_t)d * D_DIM;
    float p = 0.f;
    #pragma unroll
    for (int u = 0; u < 8; ++u){
      ushort4 a = *(const ushort4*)(row + u*256 + l4);
      p = fmaf(bf2f(a.x), s0[u].x, p);
      p = fmaf(bf2f(a.y), s0[u].y, p);
      p = fmaf(bf2f(a.z), s0[u].z, p);
      p = fmaf(bf2f(a.w), s0[u].w, p);
    }
    const float tk = tl[k];
    float g = 0.f;
    if (l < k) g = bf2f(row[ml[l]]) * __expf(tl[l] - tk);  // exact pair term
    p = fmaf(p, __expf(t0 - tk), g);
    float v = wave_red(p);
    if (l == 0) lgw += __logf(muw[d] + v + 1e-8f);
  }
  if (l == 0) wred[w] = lgw;
  __syncthreads();
  if (tid == 0){
    float lg = ((wred[0]+wred[1])+(wred[2]+wred[3]))
             + ((wred[4]+wred[5])+(wred[6]+wred[7]));
    atomicAdd(&acc[0], lg);
    __threadfence();                        // publish before taking ticket
    unsigned old = atomicAdd((unsigned*)&acc[3], 1u);
    if (old == CCH - 1){                    // last block: finalize
      float a0 = atomicAdd(&acc[0], 0.0f);  // device-scope reads
      float a1 = atomicAdd(&acc[1], 0.0f);
      float a2 = atomicAdd(&acc[2], 0.0f);
      float T = decode_T(Tp);
      out[0] = a0 - (T * a2 + a1 * (1.0f / BETA));
    }
  }
}

extern "C" void kernel_launch(void* const* d_in, const int* in_sizes, int n_in,
                              void* d_out, int out_size, void* d_ws, size_t ws_size,
                              hipStream_t stream) {
  const float* t_events  = (const float*)d_in[0];
  const int*   marks     = (const int*)  d_in[1];
  const void*  Tp        =               d_in[2];
  const float* log_mu    = (const float*)d_in[3];
  const float* log_alpha = (const float*)d_in[4];
  float* out = (float*)d_out;

  // ws layout (floats), zeroed region first:
  // SL[CCH*D] | contrib[D] | acc[16] || Carry[NSEG*D] | E[NSEG*D] | muw[D]
  //   | dchunk[CCH] | cumdec[CCH] | Aseg[NSEG] | sA[D*D bf16]
  float* ws      = (float*)d_ws;
  float* SL      = ws;
  float* contrib = SL + (size_t)CCH * D_DIM;
  float* acc     = contrib + D_DIM;
  float* Carry   = acc + 16;
  float* E       = Carry + (size_t)NSEG * D_DIM;
  float* muw     = E + (size_t)NSEG * D_DIM;
  float* dchunk  = muw + D_DIM;
  float* cumdec  = dchunk + CCH;
  float* Aseg    = cumdec + CCH;
  unsigned short* sA = (unsigned short*)(Aseg + NSEG);  // 16B-aligned offset

  size_t zero_floats = (size_t)CCH * D_DIM + D_DIM + 16;
  hipMemsetAsync(d_ws, 0, zero_floats * sizeof(float), stream);

  k_small      <<<74, 256, 0, stream>>>(t_events, marks, Tp, log_mu, muw,
                                        contrib, SL, dchunk, cumdec, Aseg, acc);
  k_scan_local <<<NSEG*8, 256, 0, stream>>>(SL, dchunk, Carry);
  k_carry_alpha<<<520, 256, 0, stream>>>(Carry, Aseg, E, log_alpha,
                                         contrib, sA, acc);
  k_events     <<<CCH, 512, 0, stream>>>(t_events, marks, sA, muw,
                                         SL, E, cumdec, acc, Tp, out);
}